// Round 3
// baseline (698.736 us; speedup 1.0000x reference)
//
#include <hip/hip_runtime.h>

#define NB 8
#define TQv 2048
#define TKv 2048
#define FD 1024
#define HD 1024

typedef __attribute__((ext_vector_type(8))) short short8;
typedef __attribute__((ext_vector_type(8))) _Float16 half8;
typedef __attribute__((ext_vector_type(4))) float f32x4;

// round-to-nearest-even fp32 -> bf16 (finite inputs only)
__device__ __forceinline__ short f2bf(float f) {
    union { float f; unsigned u; } v; v.f = f;
    unsigned r = v.u + 0x7FFFu + ((v.u >> 16) & 1u);
    return (short)(r >> 16);
}

// async 16B global -> LDS (global_load_lds_dwordx4); LDS dest = wave-uniform base + lane*16
__device__ __forceinline__ void async16(const short* g, short* l) {
    __builtin_amdgcn_global_load_lds(
        (const __attribute__((address_space(1))) unsigned int*)g,
        (__attribute__((address_space(3))) unsigned int*)l, 16, 0, 0);
}

// ---- m97-style GEMM core: NT form, C[m][n] = sum_k A[m][k] * Bt[n][k] ----
// tile 128(M) x 128(N), BK=32, 256 threads = 4 waves (2x2), acc 4x4 per wave.
// FP16MODE: same byte-level staging; MFMA dtype picked by caller flag.
template <bool F16>
__device__ __forceinline__ void gemm128_core(const short* __restrict__ A, int lda,
                                             const short* __restrict__ B, int ldb,
                                             int K, short* As, short* Bs,
                                             f32x4 acc[4][4], int tid) {
    int wave = tid >> 6, lane = tid & 63;
    int lrow = lane >> 2;          // 0..15
    int lcol = (lane & 3) << 3;    // element offset 0,8,16,24
    const short* ga0 = A + (size_t)(wave * 32 + lrow) * lda + lcol;
    const short* ga1 = ga0 + (size_t)16 * lda;
    const short* gb0 = B + (size_t)(wave * 32 + lrow) * ldb + lcol;
    const short* gb1 = gb0 + (size_t)16 * ldb;
    short* la0 = As + (wave * 32) * 32;
    short* la1 = As + (wave * 32 + 16) * 32;
    short* lb0 = Bs + (wave * 32) * 32;
    short* lb1 = Bs + (wave * 32 + 16) * 32;
    int mrow = (wave & 1) * 64 + (lane & 15);
    int ncol = (wave >> 1) * 64 + (lane & 15);
    int q8 = (lane >> 4) << 3;

    for (int k0 = 0; k0 < K; k0 += 32) {
        __syncthreads();
        async16(ga0, la0);
        async16(ga1, la1);
        async16(gb0, lb0);
        async16(gb1, lb1);
        ga0 += 32; ga1 += 32; gb0 += 32; gb1 += 32;
        __syncthreads();
#pragma unroll
        for (int mt = 0; mt < 4; ++mt) {
            if (F16) {
                half8 a = *(const half8*)(As + (mrow + mt * 16) * 32 + q8);
#pragma unroll
                for (int nt = 0; nt < 4; ++nt) {
                    half8 bfr = *(const half8*)(Bs + (ncol + nt * 16) * 32 + q8);
                    acc[mt][nt] = __builtin_amdgcn_mfma_f32_16x16x32_f16(a, bfr,
                                                                         acc[mt][nt], 0, 0, 0);
                }
            } else {
                short8 a = *(const short8*)(As + (mrow + mt * 16) * 32 + q8);
#pragma unroll
                for (int nt = 0; nt < 4; ++nt) {
                    short8 bfr = *(const short8*)(Bs + (ncol + nt * 16) * 32 + q8);
                    acc[mt][nt] = __builtin_amdgcn_mfma_f32_16x16x32_bf16(a, bfr,
                                                                          acc[mt][nt], 0, 0, 0);
                }
            }
        }
    }
}
#define ACC_INIT {{{0.f,0.f,0.f,0.f},{0.f,0.f,0.f,0.f},{0.f,0.f,0.f,0.f},{0.f,0.f,0.f,0.f}}, \
                  {{0.f,0.f,0.f,0.f},{0.f,0.f,0.f,0.f},{0.f,0.f,0.f,0.f},{0.f,0.f,0.f,0.f}}, \
                  {{0.f,0.f,0.f,0.f},{0.f,0.f,0.f,0.f},{0.f,0.f,0.f,0.f},{0.f,0.f,0.f,0.f}}, \
                  {{0.f,0.f,0.f,0.f},{0.f,0.f,0.f,0.f},{0.f,0.f,0.f,0.f},{0.f,0.f,0.f,0.f}}}
// epilogue: row = (lane>>4)*4 + r (within 16), col = lane&15
#define EPI_GM(mt, r) (tile_m + (wave & 1) * 64 + (mt) * 16 + ((lane >> 4) << 2) + (r))
#define EPI_GN(nt)    (tile_n + (wave >> 1) * 64 + (nt) * 16 + (lane & 15))

// ---- fp32 -> bf16 pre-pass for query & encoder_states ----
__global__ __launch_bounds__(256) void convert_kernel(const float* __restrict__ q,
                                                      const float* __restrict__ e,
                                                      short* __restrict__ xq,
                                                      short* __restrict__ xe) {
    size_t i = (size_t)blockIdx.x * 256 + threadIdx.x;
    const float* src = blockIdx.y ? e : q;
    short* dst = blockIdx.y ? xe : xq;
    float4 a = ((const float4*)src)[2 * i];
    float4 b = ((const float4*)src)[2 * i + 1];
    short8 v;
    v[0] = f2bf(a.x); v[1] = f2bf(a.y); v[2] = f2bf(a.z); v[3] = f2bf(a.w);
    v[4] = f2bf(b.x); v[5] = f2bf(b.y); v[6] = f2bf(b.z); v[7] = f2bf(b.w);
    ((short8*)dst)[i] = v;
}

// ---- W[F][H] fp32 -> Wt[H][F] bf16, z picks Wq/Wk/Wv ----
__global__ __launch_bounds__(256) void wtrans_kernel(const float* __restrict__ Wq,
                                                     const float* __restrict__ Wk,
                                                     const float* __restrict__ Wv,
                                                     short* __restrict__ Wt) {
    __shared__ float tile[32][33];
    const float* W = (blockIdx.z == 0) ? Wq : (blockIdx.z == 1) ? Wk : Wv;
    short* dst = Wt + (size_t)blockIdx.z * HD * FD;
    int h0 = blockIdx.x * 32, f0 = blockIdx.y * 32;
    int tx = threadIdx.x, ty = threadIdx.y;
    for (int j = ty; j < 32; j += 8)
        tile[j][tx] = W[(size_t)(f0 + j) * HD + h0 + tx];
    __syncthreads();
    for (int j = ty; j < 32; j += 8)
        dst[(size_t)(h0 + j) * FD + f0 + tx] = f2bf(tile[tx][j]);
}

// ---- Q/K projections: z=0: Q=Xq@WqT+bq; z=1: K=Xe@WkT+bk (bf16 out) ----
__global__ __launch_bounds__(256) void projqk_kernel(const short* __restrict__ Xq,
                                                     const short* __restrict__ Xe,
                                                     const short* __restrict__ Wt3,
                                                     const float* __restrict__ bq,
                                                     const float* __restrict__ bk,
                                                     short* __restrict__ Q,
                                                     short* __restrict__ K) {
    __shared__ short As[128 * 32];
    __shared__ short Bs[128 * 32];
    int tid = threadIdx.x;
    int wave = tid >> 6, lane = tid & 63;
    int p = blockIdx.z;
    const short* X = (p == 0) ? Xq : Xe;
    const short* Wt = Wt3 + (size_t)p * HD * FD;
    const float* bias = (p == 0) ? bq : bk;
    short* O = (p == 0) ? Q : K;
    int bid = blockIdx.x;              // 0..1023; XCD swizzle: 8 n-tiles of an m-group share XCD
    int xcd = bid & 7;
    int idx = bid >> 3;
    int n_t = idx & 7;
    int m_t = (idx >> 3) * 8 + xcd;
    int tile_m = m_t * 128;
    int tile_n = n_t * 128;
    f32x4 acc[4][4] = ACC_INIT;
    gemm128_core<false>(X + (size_t)tile_m * FD, FD, Wt + (size_t)tile_n * FD, FD, FD,
                        As, Bs, acc, tid);
#pragma unroll
    for (int nt = 0; nt < 4; ++nt) {
        int gn = EPI_GN(nt);
        float bv_ = bias[gn];
#pragma unroll
        for (int mt = 0; mt < 4; ++mt)
#pragma unroll
            for (int r = 0; r < 4; ++r) {
                int gm = EPI_GM(mt, r);
                O[(size_t)gm * HD + gn] = f2bf(acc[mt][nt][r] + bv_);
            }
    }
}

// ---- V projection, transposed natively: Vt[b][h][t] = sum_f Wtv[h][f]*Xe[b][t][f] + bv[h], fp16 out ----
__global__ __launch_bounds__(256) void projv_kernel(const short* __restrict__ Xe,
                                                    const short* __restrict__ Wtv,
                                                    const float* __restrict__ bv,
                                                    short* __restrict__ Vt) {
    __shared__ short As[128 * 32];
    __shared__ short Bs[128 * 32];
    int tid = threadIdx.x;
    int wave = tid >> 6, lane = tid & 63;
    int b = blockIdx.z;
    int tile_m = blockIdx.x * 128;     // over HD
    int tile_n = blockIdx.y * 128;     // over TKv
    const short* Xb = Xe + (size_t)b * TKv * FD;
    f32x4 acc[4][4] = ACC_INIT;
    gemm128_core<false>(Wtv + (size_t)tile_m * FD, FD, Xb + (size_t)tile_n * FD, FD, FD,
                        As, Bs, acc, tid);
    short* Ob = Vt + (size_t)b * HD * TKv;
#pragma unroll
    for (int mt = 0; mt < 4; ++mt)
#pragma unroll
        for (int r = 0; r < 4; ++r) {
            int gm = EPI_GM(mt, r);     // h index
            float bv_ = bv[gm];
#pragma unroll
            for (int nt = 0; nt < 4; ++nt) {
                int gn = EPI_GN(nt);    // t index
                union { _Float16 h; short s; } cv;
                cv.h = (_Float16)(acc[mt][nt][r] + bv_);
                Ob[(size_t)gm * TKv + gn] = cv.s;
            }
        }
}

// ---- mask int32 -> bitmask u64 (ballot), + zero the row-sum array L ----
__global__ __launch_bounds__(256) void maskbits_kernel(const int* __restrict__ mask,
                                                       unsigned long long* __restrict__ Mbits,
                                                       float* __restrict__ L) {
    int tid = threadIdx.x;
    int lane = tid & 63;
    if (blockIdx.x < 64) L[blockIdx.x * 256 + tid] = 0.f;
    const int NW = NB * TQv * (TKv / 64);  // 524288 words
    int stride = gridDim.x * 4;
    for (int w = blockIdx.x * 4 + (tid >> 6); w < NW; w += stride) {
        int v = mask[(size_t)w * 64 + lane];
        unsigned long long bal = __ballot(v != 0);
        if (lane == 0) Mbits[w] = bal;
    }
}

// ---- score: P'[b][q][k] = mask ? exp(QK/32 - 4) : 0 (fp16), row-partials -> atomicAdd L ----
__global__ __launch_bounds__(256) void score_kernel(const short* __restrict__ Q,
                                                    const short* __restrict__ K,
                                                    const unsigned long long* __restrict__ Mbits,
                                                    short* __restrict__ S,
                                                    float* __restrict__ L) {
    __shared__ short As[128 * 32];
    __shared__ short Bs[128 * 32];
    int tid = threadIdx.x;
    int wave = tid >> 6, lane = tid & 63;
    int b = blockIdx.z;
    int tile_m = blockIdx.x * 128;
    int tile_n = blockIdx.y * 128;
    const short* Aq = Q + (size_t)b * TQv * HD;
    const short* Bk = K + (size_t)b * TKv * HD;
    f32x4 acc[4][4] = ACC_INIT;
    gemm128_core<false>(Aq + (size_t)tile_m * HD, HD, Bk + (size_t)tile_n * HD, HD, HD,
                        As, Bs, acc, tid);
    short* Sb = S + (size_t)b * TQv * TKv;
    const unsigned long long* Mb = Mbits + (size_t)b * TQv * (TKv / 64);
    float* Lb = L + (size_t)b * TQv;
    int w = (tile_n >> 6) + (wave >> 1);
    int l15 = lane & 15;
#pragma unroll
    for (int mt = 0; mt < 4; ++mt)
#pragma unroll
        for (int r = 0; r < 4; ++r) {
            int gm = EPI_GM(mt, r);
            unsigned long long bits = Mb[(size_t)gm * (TKv / 64) + w];
            float rs = 0.f;
#pragma unroll
            for (int nt = 0; nt < 4; ++nt) {
                int gn = EPI_GN(nt);
                float s = acc[mt][nt][r] * 0.03125f;
                float p = ((bits >> (nt * 16 + l15)) & 1ULL)
                              ? exp2f((s - 4.0f) * 1.44269504f) : 0.f;
                rs += p;
                union { _Float16 h; short sh; } cv;
                cv.h = (_Float16)p;
                Sb[(size_t)gm * TKv + gn] = cv.sh;
            }
            for (int sh = 1; sh < 16; sh <<= 1) rs += __shfl_xor(rs, sh);
            if (l15 == 0) atomicAdd(&Lb[gm], rs);
        }
}

// ---- pv: O[b][q][h] = (sum_k P'[q,k] * Vt[h,k]) / L[q], fp16 MFMA, fp32 out ----
__global__ __launch_bounds__(256) void pv_kernel(const short* __restrict__ P,
                                                 const short* __restrict__ Vt,
                                                 const float* __restrict__ L,
                                                 float* __restrict__ Out) {
    __shared__ short As[128 * 32];
    __shared__ short Bs[128 * 32];
    int tid = threadIdx.x;
    int wave = tid >> 6, lane = tid & 63;
    int b = blockIdx.z;
    int tile_m = blockIdx.x * 128;     // over TQv
    int tile_n = blockIdx.y * 128;     // over HD
    const short* Ap = P + (size_t)b * TQv * TKv;
    const short* Bv = Vt + (size_t)b * HD * TKv;
    const float* Lb = L + (size_t)b * TQv;
    f32x4 acc[4][4] = ACC_INIT;
    gemm128_core<true>(Ap + (size_t)tile_m * TKv, TKv, Bv + (size_t)tile_n * TKv, TKv, TKv,
                       As, Bs, acc, tid);
    float* Ob = Out + (size_t)b * TQv * HD;
#pragma unroll
    for (int mt = 0; mt < 4; ++mt)
#pragma unroll
        for (int r = 0; r < 4; ++r) {
            int gm = EPI_GM(mt, r);
            float l = Lb[gm];
            float inv = (l > 0.f) ? 1.f / l : 0.f;
#pragma unroll
            for (int nt = 0; nt < 4; ++nt) {
                int gn = EPI_GN(nt);
                Ob[(size_t)gm * HD + gn] = acc[mt][nt][r] * inv;
            }
        }
}

extern "C" void kernel_launch(void* const* d_in, const int* in_sizes, int n_in,
                              void* d_out, int out_size, void* d_ws, size_t ws_size,
                              hipStream_t stream) {
    const float* query = (const float*)d_in[0];
    const float* enc   = (const float*)d_in[1];
    const int*   mask  = (const int*)d_in[2];
    const float* Wq    = (const float*)d_in[3];
    const float* bq    = (const float*)d_in[4];
    const float* Wk    = (const float*)d_in[5];
    const float* bk    = (const float*)d_in[6];
    const float* Wv    = (const float*)d_in[7];
    const float* bv    = (const float*)d_in[8];
    float* out = (float*)d_out;

    // workspace layout (bytes); total 174,063,616
    //   Wt region [0, 6.29MB): bf16 Wtq/Wtk/Wtv (wtrans->projv), then REUSED after projv
    //     as Mbits (4 MB, maskbits->score) + L (64 KB row sums, score->pv).
    //   S (fp16 P', 67 MB) aliases Xq+Xe which die after projqk/projv.
    char* ws = (char*)d_ws;
    short* Wt  = (short*)(ws);
    unsigned long long* Mbits = (unsigned long long*)(ws);
    float* L   = (float*)(ws + 4194304);
    short* Xq  = (short*)(ws + 6291456);
    short* Xe  = (short*)(ws + 39845888);
    short* S   = (short*)(ws + 6291456);       // aliases Xq,Xe
    short* Qb  = (short*)(ws + 73400320);
    short* Kb  = (short*)(ws + 106954752);
    short* Vt  = (short*)(ws + 140509184);
    (void)in_sizes; (void)n_in; (void)out_size; (void)ws_size;

    convert_kernel<<<dim3(8192, 2), 256, 0, stream>>>(query, enc, Xq, Xe);
    wtrans_kernel<<<dim3(32, 32, 3), dim3(32, 8), 0, stream>>>(Wq, Wk, Wv, Wt);
    projqk_kernel<<<dim3(1024, 1, 2), 256, 0, stream>>>(Xq, Xe, Wt, bq, bk, Qb, Kb);
    projv_kernel<<<dim3(8, 16, 8), 256, 0, stream>>>(Xe, Wt + (size_t)2 * HD * FD, bv, Vt);
    maskbits_kernel<<<dim3(2048), 256, 0, stream>>>(mask, Mbits, L);
    score_kernel<<<dim3(16, 16, 8), 256, 0, stream>>>(Qb, Kb, Mbits, S, L);
    pv_kernel<<<dim3(16, 8, 8), 256, 0, stream>>>(S, Vt, L, out);
}

// Round 4
// 667.370 us; speedup vs baseline: 1.0470x; 1.0470x over previous
//
#include <hip/hip_runtime.h>

#define NB 8
#define TQv 2048
#define TKv 2048
#define FD 1024
#define HD 1024

typedef __attribute__((ext_vector_type(8))) short short8;
typedef __attribute__((ext_vector_type(8))) _Float16 half8;
typedef __attribute__((ext_vector_type(16))) float f32x16;

// round-to-nearest-even fp32 -> bf16 (finite inputs only)
__device__ __forceinline__ short f2bf(float f) {
    union { float f; unsigned u; } v; v.f = f;
    unsigned r = v.u + 0x7FFFu + ((v.u >> 16) & 1u);
    return (short)(r >> 16);
}

// async 16B global -> LDS (global_load_lds_dwordx4); LDS dest = wave-uniform base + lane*16
__device__ __forceinline__ void async16(const short* g, short* l) {
    __builtin_amdgcn_global_load_lds(
        (const __attribute__((address_space(1))) unsigned int*)g,
        (__attribute__((address_space(3))) unsigned int*)l, 16, 0, 0);
}

// ---- GEMM core, 32x32x16 MFMA: NT form, C[m][n] = sum_k A[m][k] * Bt[n][k] ----
// tile 128(M) x 128(N), BK=32, 256 threads = 4 waves (2x2 of 64x64), acc 2x2 f32x16/wave.
// Per K=32 step: 8 ds_read_b128 + 8 MFMA (vs 8 + 16 for 16x16x32) -> ~15% fewer MFMA cycles.
template <bool F16>
__device__ __forceinline__ void gemm128_core(const short* __restrict__ A, int lda,
                                             const short* __restrict__ B, int ldb,
                                             int K, short* As, short* Bs,
                                             f32x16 acc[2][2], int tid) {
    int wave = tid >> 6, lane = tid & 63;
    int lrow = lane >> 2;          // 0..15
    int lcol = (lane & 3) << 3;    // 0,8,16,24
    const short* ga0 = A + (size_t)(wave * 32 + lrow) * lda + lcol;
    const short* ga1 = ga0 + (size_t)16 * lda;
    const short* gb0 = B + (size_t)(wave * 32 + lrow) * ldb + lcol;
    const short* gb1 = gb0 + (size_t)16 * ldb;
    short* la0 = As + (wave * 32) * 32;
    short* la1 = As + (wave * 32 + 16) * 32;
    short* lb0 = Bs + (wave * 32) * 32;
    short* lb1 = Bs + (wave * 32 + 16) * 32;
    // A-frag for 32x32x16: m = lane&31, k = (lane>>5)*8 + j  (8 contiguous shorts)
    int mbase = (wave & 1) * 64 + (lane & 31);
    int nbase = (wave >> 1) * 64 + (lane & 31);
    int kh = (lane >> 5) << 3;     // 0 or 8

    for (int k0 = 0; k0 < K; k0 += 32) {
        __syncthreads();
        async16(ga0, la0);
        async16(ga1, la1);
        async16(gb0, lb0);
        async16(gb1, lb1);
        ga0 += 32; ga1 += 32; gb0 += 32; gb1 += 32;
        __syncthreads();
        if (F16) {
            half8 af[2][2], bf[2][2];
#pragma unroll
            for (int mt = 0; mt < 2; ++mt)
#pragma unroll
                for (int ks = 0; ks < 2; ++ks) {
                    af[mt][ks] = *(const half8*)(As + (mbase + mt * 32) * 32 + ks * 16 + kh);
                    bf[mt][ks] = *(const half8*)(Bs + (nbase + mt * 32) * 32 + ks * 16 + kh);
                }
#pragma unroll
            for (int ks = 0; ks < 2; ++ks)
#pragma unroll
                for (int mt = 0; mt < 2; ++mt)
#pragma unroll
                    for (int nt = 0; nt < 2; ++nt)
                        acc[mt][nt] = __builtin_amdgcn_mfma_f32_32x32x16_f16(
                            af[mt][ks], bf[nt][ks], acc[mt][nt], 0, 0, 0);
        } else {
            short8 af[2][2], bf[2][2];
#pragma unroll
            for (int mt = 0; mt < 2; ++mt)
#pragma unroll
                for (int ks = 0; ks < 2; ++ks) {
                    af[mt][ks] = *(const short8*)(As + (mbase + mt * 32) * 32 + ks * 16 + kh);
                    bf[mt][ks] = *(const short8*)(Bs + (nbase + mt * 32) * 32 + ks * 16 + kh);
                }
#pragma unroll
            for (int ks = 0; ks < 2; ++ks)
#pragma unroll
                for (int mt = 0; mt < 2; ++mt)
#pragma unroll
                    for (int nt = 0; nt < 2; ++nt)
                        acc[mt][nt] = __builtin_amdgcn_mfma_f32_32x32x16_bf16(
                            af[mt][ks], bf[nt][ks], acc[mt][nt], 0, 0, 0);
        }
    }
}
#define ACC0 {0.f,0.f,0.f,0.f,0.f,0.f,0.f,0.f,0.f,0.f,0.f,0.f,0.f,0.f,0.f,0.f}
#define ACC_INIT {{ACC0, ACC0}, {ACC0, ACC0}}
// C/D layout (verified m74/m101): col = lane&31; row = 4*(lane>>5) + 8*(r>>2) + (r&3)
#define EPI_GM(mt, r) (tile_m + (wave & 1) * 64 + (mt) * 32 + ((lane >> 5) << 2) + (((r) >> 2) << 3) + ((r) & 3))
#define EPI_GN(nt)    (tile_n + (wave >> 1) * 64 + (nt) * 32 + (lane & 31))

// ---- fp32 -> bf16 pre-pass for query & encoder_states ----
__global__ __launch_bounds__(256) void convert_kernel(const float* __restrict__ q,
                                                      const float* __restrict__ e,
                                                      short* __restrict__ xq,
                                                      short* __restrict__ xe) {
    size_t i = (size_t)blockIdx.x * 256 + threadIdx.x;
    const float* src = blockIdx.y ? e : q;
    short* dst = blockIdx.y ? xe : xq;
    float4 a = ((const float4*)src)[2 * i];
    float4 b = ((const float4*)src)[2 * i + 1];
    short8 v;
    v[0] = f2bf(a.x); v[1] = f2bf(a.y); v[2] = f2bf(a.z); v[3] = f2bf(a.w);
    v[4] = f2bf(b.x); v[5] = f2bf(b.y); v[6] = f2bf(b.z); v[7] = f2bf(b.w);
    ((short8*)dst)[i] = v;
}

// ---- W[F][H] fp32 -> Wt[H][F] bf16, z picks Wq/Wk/Wv ----
__global__ __launch_bounds__(256) void wtrans_kernel(const float* __restrict__ Wq,
                                                     const float* __restrict__ Wk,
                                                     const float* __restrict__ Wv,
                                                     short* __restrict__ Wt) {
    __shared__ float tile[32][33];
    const float* W = (blockIdx.z == 0) ? Wq : (blockIdx.z == 1) ? Wk : Wv;
    short* dst = Wt + (size_t)blockIdx.z * HD * FD;
    int h0 = blockIdx.x * 32, f0 = blockIdx.y * 32;
    int tx = threadIdx.x, ty = threadIdx.y;
    for (int j = ty; j < 32; j += 8)
        tile[j][tx] = W[(size_t)(f0 + j) * HD + h0 + tx];
    __syncthreads();
    for (int j = ty; j < 32; j += 8)
        dst[(size_t)(h0 + j) * FD + f0 + tx] = f2bf(tile[tx][j]);
}

// ---- Q/K projections ----
__global__ __launch_bounds__(256, 4) void projqk_kernel(const short* __restrict__ Xq,
                                                        const short* __restrict__ Xe,
                                                        const short* __restrict__ Wt3,
                                                        const float* __restrict__ bq,
                                                        const float* __restrict__ bk,
                                                        short* __restrict__ Q,
                                                        short* __restrict__ K) {
    __shared__ short As[128 * 32];
    __shared__ short Bs[128 * 32];
    int tid = threadIdx.x;
    int wave = tid >> 6, lane = tid & 63;
    int p = blockIdx.z;
    const short* X = (p == 0) ? Xq : Xe;
    const short* Wt = Wt3 + (size_t)p * HD * FD;
    const float* bias = (p == 0) ? bq : bk;
    short* O = (p == 0) ? Q : K;
    int bid = blockIdx.x;              // XCD swizzle: m-groups bound to XCDs
    int xcd = bid & 7;
    int idx = bid >> 3;
    int n_t = idx & 7;
    int m_t = (idx >> 3) * 8 + xcd;
    int tile_m = m_t * 128;
    int tile_n = n_t * 128;
    f32x16 acc[2][2] = ACC_INIT;
    gemm128_core<false>(X + (size_t)tile_m * FD, FD, Wt + (size_t)tile_n * FD, FD, FD,
                        As, Bs, acc, tid);
#pragma unroll
    for (int nt = 0; nt < 2; ++nt) {
        int gn = EPI_GN(nt);
        float bv_ = bias[gn];
#pragma unroll
        for (int mt = 0; mt < 2; ++mt)
#pragma unroll
            for (int r = 0; r < 16; ++r) {
                int gm = EPI_GM(mt, r);
                O[(size_t)gm * HD + gn] = f2bf(acc[mt][nt][r] + bv_);
            }
    }
}

// ---- V projection, transposed natively: Vt[b][h][t] = Wtv[h,:].Xe[b,t,:] + bv[h], fp16 out ----
// batch -> XCD binding: id&7 = b
__global__ __launch_bounds__(256, 4) void projv_kernel(const short* __restrict__ Xe,
                                                       const short* __restrict__ Wtv,
                                                       const float* __restrict__ bv,
                                                       short* __restrict__ Vt) {
    __shared__ short As[128 * 32];
    __shared__ short Bs[128 * 32];
    int tid = threadIdx.x;
    int wave = tid >> 6, lane = tid & 63;
    int id = blockIdx.x;
    int b = id & 7;
    int i = id >> 3;                   // 0..127
    int n_t = i & 15;                  // over TKv
    int m_t = i >> 4;                  // over HD
    int tile_m = m_t * 128;
    int tile_n = n_t * 128;
    const short* Xb = Xe + (size_t)b * TKv * FD;
    f32x16 acc[2][2] = ACC_INIT;
    gemm128_core<false>(Wtv + (size_t)tile_m * FD, FD, Xb + (size_t)tile_n * FD, FD, FD,
                        As, Bs, acc, tid);
    short* Ob = Vt + (size_t)b * HD * TKv;
#pragma unroll
    for (int mt = 0; mt < 2; ++mt)
#pragma unroll
        for (int r = 0; r < 16; ++r) {
            int gm = EPI_GM(mt, r);     // h
            float bv_ = bv[gm];
#pragma unroll
            for (int nt = 0; nt < 2; ++nt) {
                int gn = EPI_GN(nt);    // t
                union { _Float16 h; short s; } cv;
                cv.h = (_Float16)(acc[mt][nt][r] + bv_);
                Ob[(size_t)gm * TKv + gn] = cv.s;
            }
        }
}

// ---- mask int32 -> bitmask u64 (ballot), + zero row-sum array L ----
__global__ __launch_bounds__(256) void maskbits_kernel(const int* __restrict__ mask,
                                                       unsigned long long* __restrict__ Mbits,
                                                       float* __restrict__ L) {
    int tid = threadIdx.x;
    int lane = tid & 63;
    if (blockIdx.x < 64) L[blockIdx.x * 256 + tid] = 0.f;
    const int NW = NB * TQv * (TKv / 64);
    int stride = gridDim.x * 4;
    for (int w = blockIdx.x * 4 + (tid >> 6); w < NW; w += stride) {
        int v = mask[(size_t)w * 64 + lane];
        unsigned long long bal = __ballot(v != 0);
        if (lane == 0) Mbits[w] = bal;
    }
}

// ---- score: P' = mask ? exp(QK/32 - 4) : 0 (fp16), row partials -> atomicAdd L ----
__global__ __launch_bounds__(256, 4) void score_kernel(const short* __restrict__ Q,
                                                       const short* __restrict__ K,
                                                       const unsigned long long* __restrict__ Mbits,
                                                       short* __restrict__ S,
                                                       float* __restrict__ L) {
    __shared__ short As[128 * 32];
    __shared__ short Bs[128 * 32];
    int tid = threadIdx.x;
    int wave = tid >> 6, lane = tid & 63;
    int id = blockIdx.x;
    int b = id & 7;
    int i = id >> 3;                   // 0..255
    int n_t = i & 15;
    int m_t = i >> 4;
    int tile_m = m_t * 128;
    int tile_n = n_t * 128;
    const short* Aq = Q + (size_t)b * TQv * HD;
    const short* Bk = K + (size_t)b * TKv * HD;
    f32x16 acc[2][2] = ACC_INIT;
    gemm128_core<false>(Aq + (size_t)tile_m * HD, HD, Bk + (size_t)tile_n * HD, HD, HD,
                        As, Bs, acc, tid);
    short* Sb = S + (size_t)b * TQv * TKv;
    const unsigned long long* Mb = Mbits + (size_t)b * TQv * (TKv / 64);
    float* Lb = L + (size_t)b * TQv;
    int wofs = (tile_n >> 6) + (wave >> 1);
    int l31 = lane & 31;
#pragma unroll
    for (int mt = 0; mt < 2; ++mt)
#pragma unroll
        for (int r = 0; r < 16; ++r) {
            int gm = EPI_GM(mt, r);
            unsigned long long bits = Mb[(size_t)gm * (TKv / 64) + wofs];
            float rs = 0.f;
#pragma unroll
            for (int nt = 0; nt < 2; ++nt) {
                int gn = EPI_GN(nt);
                float s = acc[mt][nt][r] * 0.03125f;
                float p = ((bits >> (nt * 32 + l31)) & 1ULL)
                              ? exp2f((s - 4.0f) * 1.44269504f) : 0.f;
                rs += p;
                union { _Float16 h; short sh; } cv;
                cv.h = (_Float16)p;
                Sb[(size_t)gm * TKv + gn] = cv.sh;
            }
            for (int sh = 1; sh < 32; sh <<= 1) rs += __shfl_xor(rs, sh);
            if (l31 == 0) atomicAdd(&Lb[gm], rs);
        }
}

// ---- pv: O = (P' . Vt^T) / L, fp16 MFMA, fp32 out ----
__global__ __launch_bounds__(256, 4) void pv_kernel(const short* __restrict__ P,
                                                    const short* __restrict__ Vt,
                                                    const float* __restrict__ L,
                                                    float* __restrict__ Out) {
    __shared__ short As[128 * 32];
    __shared__ short Bs[128 * 32];
    int tid = threadIdx.x;
    int wave = tid >> 6, lane = tid & 63;
    int id = blockIdx.x;
    int b = id & 7;
    int i = id >> 3;                   // 0..127
    int n_t = i & 7;                   // over HD
    int m_t = i >> 3;                  // over TQv
    int tile_m = m_t * 128;
    int tile_n = n_t * 128;
    const short* Ap = P + (size_t)b * TQv * TKv;
    const short* Bv = Vt + (size_t)b * HD * TKv;
    const float* Lb = L + (size_t)b * TQv;
    f32x16 acc[2][2] = ACC_INIT;
    gemm128_core<true>(Ap + (size_t)tile_m * TKv, TKv, Bv + (size_t)tile_n * TKv, TKv, TKv,
                       As, Bs, acc, tid);
    float* Ob = Out + (size_t)b * TQv * HD;
#pragma unroll
    for (int mt = 0; mt < 2; ++mt)
#pragma unroll
        for (int r = 0; r < 16; ++r) {
            int gm = EPI_GM(mt, r);
            float l = Lb[gm];
            float inv = (l > 0.f) ? 1.f / l : 0.f;
#pragma unroll
            for (int nt = 0; nt < 2; ++nt) {
                int gn = EPI_GN(nt);
                Ob[(size_t)gm * HD + gn] = acc[mt][nt][r] * inv;
            }
        }
}

extern "C" void kernel_launch(void* const* d_in, const int* in_sizes, int n_in,
                              void* d_out, int out_size, void* d_ws, size_t ws_size,
                              hipStream_t stream) {
    const float* query = (const float*)d_in[0];
    const float* enc   = (const float*)d_in[1];
    const int*   mask  = (const int*)d_in[2];
    const float* Wq    = (const float*)d_in[3];
    const float* bq    = (const float*)d_in[4];
    const float* Wk    = (const float*)d_in[5];
    const float* bk    = (const float*)d_in[6];
    const float* Wv    = (const float*)d_in[7];
    const float* bv    = (const float*)d_in[8];
    float* out = (float*)d_out;

    // workspace layout (bytes); total 174,063,616
    //   [0, 6.29MB): Wtq/Wtk/Wtv bf16 (wtrans -> projqk/projv), then reused:
    //     Mbits [0,4MB) overwrites Wtq/Wtk (dead after projqk);
    //     L [4MB, 4MB+64KB) overwrites Wtv start (dead after projv; maskbits runs after projv? no:
    //     maskbits runs after projv in the launch order below, so safe).
    //   S (fp16 P', 67MB) aliases Xq+Xe (dead after projqk/projv).
    char* ws = (char*)d_ws;
    short* Wt  = (short*)(ws);
    unsigned long long* Mbits = (unsigned long long*)(ws);
    float* L   = (float*)(ws + 4194304);
    short* Xq  = (short*)(ws + 6291456);
    short* Xe  = (short*)(ws + 39845888);
    short* S   = (short*)(ws + 6291456);       // aliases Xq,Xe
    short* Qb  = (short*)(ws + 73400320);
    short* Kb  = (short*)(ws + 106954752);
    short* Vt  = (short*)(ws + 140509184);
    (void)in_sizes; (void)n_in; (void)out_size; (void)ws_size;

    convert_kernel<<<dim3(8192, 2), 256, 0, stream>>>(query, enc, Xq, Xe);
    wtrans_kernel<<<dim3(32, 32, 3), dim3(32, 8), 0, stream>>>(Wq, Wk, Wv, Wt);
    projqk_kernel<<<dim3(1024, 1, 2), 256, 0, stream>>>(Xq, Xe, Wt, bq, bk, Qb, Kb);
    projv_kernel<<<dim3(1024), 256, 0, stream>>>(Xe, Wt + (size_t)2 * HD * FD, bv, Vt);
    maskbits_kernel<<<dim3(2048), 256, 0, stream>>>(mask, Mbits, L);
    score_kernel<<<dim3(2048), 256, 0, stream>>>(Qb, Kb, Mbits, S, L);
    pv_kernel<<<dim3(1024), 256, 0, stream>>>(S, Vt, L, out);
}

// Round 5
// 629.022 us; speedup vs baseline: 1.1108x; 1.0610x over previous
//
#include <hip/hip_runtime.h>

#define NB 8
#define TQv 2048
#define TKv 2048
#define FD 1024
#define HD 1024

typedef __attribute__((ext_vector_type(8))) short short8;
typedef __attribute__((ext_vector_type(8))) _Float16 half8;
typedef __attribute__((ext_vector_type(16))) float f32x16;

// round-to-nearest-even fp32 -> bf16 (finite inputs only)
__device__ __forceinline__ short f2bf(float f) {
    union { float f; unsigned u; } v; v.f = f;
    unsigned r = v.u + 0x7FFFu + ((v.u >> 16) & 1u);
    return (short)(r >> 16);
}

// async 16B global -> LDS (global_load_lds_dwordx4); LDS dest = wave-uniform base + lane*16
__device__ __forceinline__ void async16(const short* g, short* l) {
    __builtin_amdgcn_global_load_lds(
        (const __attribute__((address_space(1))) unsigned int*)g,
        (__attribute__((address_space(3))) unsigned int*)l, 16, 0, 0);
}

// ---- GEMM core, 32x32x16 MFMA, XOR-swizzled LDS, BK=64 ----
// NT form: C[m][n] = sum_k A[m][k] * Bt[n][k]; tile 128(M) x 128(N),
// 256 threads = 4 waves (2x2 of 64x64), acc 2x2 f32x16 per wave.
// LDS layout: element (r,k) lives in 16-B block L = 8r + ((k>>3) ^ (r&7)), byte (k&7)*2.
//   - fragment read (rows r..r+31, fixed k-chunk): L%8 = kc^(r&7) sweeps all 8 values
//     over 8 consecutive rows -> all 32 banks hit evenly -> conflict-free.
//   - staging call = 64 consecutive blocks = 8 rows x 8 chunks; lane l takes
//     row lr=l>>3, chunk kc=(l&7)^lr -> per row 128 contiguous global bytes (coalesced).
template <bool F16>
__device__ __forceinline__ void gemm128_core(const short* __restrict__ A, int lda,
                                             const short* __restrict__ B, int ldb,
                                             int K, short* As, short* Bs,
                                             f32x16 acc[2][2], int tid) {
    int wave = tid >> 6, lane = tid & 63;
    int lr = lane >> 3;                // row within 8-row window
    int kc = (lane & 7) ^ lr;          // swizzled chunk this lane fetches
    const short* ga[4]; const short* gb[4];
    short* la[4]; short* lb[4];
#pragma unroll
    for (int j = 0; j < 4; ++j) {
        int w = wave + 4 * j;          // window index 0..15 (8 rows each)
        ga[j] = A + (size_t)(8 * w + lr) * lda + kc * 8;
        gb[j] = B + (size_t)(8 * w + lr) * ldb + kc * 8;
        la[j] = As + w * 512;          // 64 blocks * 8 shorts
        lb[j] = Bs + w * 512;
    }
    int mbase = (wave & 1) * 64 + (lane & 31);
    int nbase = (wave >> 1) * 64 + (lane & 31);
    int khalf = lane >> 5;             // 0/1: k-offset 0 or 8 within 16
    int l7 = lane & 7;                 // (row&7) for this lane's fragment rows

    for (int k0 = 0; k0 < K; k0 += 64) {
        __syncthreads();
#pragma unroll
        for (int j = 0; j < 4; ++j) { async16(ga[j], la[j]); async16(gb[j], lb[j]); }
#pragma unroll
        for (int j = 0; j < 4; ++j) { ga[j] += 64; gb[j] += 64; }
        __syncthreads();
#pragma unroll
        for (int ks = 0; ks < 4; ++ks) {
            int kcc = 2 * ks + khalf;
            int sw = kcc ^ l7;
            if (F16) {
                half8 af[2], bf[2];
#pragma unroll
                for (int mt = 0; mt < 2; ++mt) {
                    af[mt] = *(const half8*)(As + ((mbase + mt * 32) * 8 + sw) * 8);
                    bf[mt] = *(const half8*)(Bs + ((nbase + mt * 32) * 8 + sw) * 8);
                }
#pragma unroll
                for (int mt = 0; mt < 2; ++mt)
#pragma unroll
                    for (int nt = 0; nt < 2; ++nt)
                        acc[mt][nt] = __builtin_amdgcn_mfma_f32_32x32x16_f16(
                            af[mt], bf[nt], acc[mt][nt], 0, 0, 0);
            } else {
                short8 af[2], bf[2];
#pragma unroll
                for (int mt = 0; mt < 2; ++mt) {
                    af[mt] = *(const short8*)(As + ((mbase + mt * 32) * 8 + sw) * 8);
                    bf[mt] = *(const short8*)(Bs + ((nbase + mt * 32) * 8 + sw) * 8);
                }
#pragma unroll
                for (int mt = 0; mt < 2; ++mt)
#pragma unroll
                    for (int nt = 0; nt < 2; ++nt)
                        acc[mt][nt] = __builtin_amdgcn_mfma_f32_32x32x16_bf16(
                            af[mt], bf[nt], acc[mt][nt], 0, 0, 0);
            }
        }
    }
}
#define ACC0 {0.f,0.f,0.f,0.f,0.f,0.f,0.f,0.f,0.f,0.f,0.f,0.f,0.f,0.f,0.f,0.f}
#define ACC_INIT {{ACC0, ACC0}, {ACC0, ACC0}}
// C/D layout (verified m74/m101): col = lane&31; row = 4*(lane>>5) + 8*(r>>2) + (r&3)
#define EPI_GM(mt, r) (tile_m + (wave & 1) * 64 + (mt) * 32 + ((lane >> 5) << 2) + (((r) >> 2) << 3) + ((r) & 3))
#define EPI_GN(nt)    (tile_n + (wave >> 1) * 64 + (nt) * 32 + (lane & 31))

// ---- fp32 -> bf16 pre-pass for query & encoder_states ----
__global__ __launch_bounds__(256) void convert_kernel(const float* __restrict__ q,
                                                      const float* __restrict__ e,
                                                      short* __restrict__ xq,
                                                      short* __restrict__ xe) {
    size_t i = (size_t)blockIdx.x * 256 + threadIdx.x;
    const float* src = blockIdx.y ? e : q;
    short* dst = blockIdx.y ? xe : xq;
    float4 a = ((const float4*)src)[2 * i];
    float4 b = ((const float4*)src)[2 * i + 1];
    short8 v;
    v[0] = f2bf(a.x); v[1] = f2bf(a.y); v[2] = f2bf(a.z); v[3] = f2bf(a.w);
    v[4] = f2bf(b.x); v[5] = f2bf(b.y); v[6] = f2bf(b.z); v[7] = f2bf(b.w);
    ((short8*)dst)[i] = v;
}

// ---- W[F][H] fp32 -> Wt[H][F] bf16, z picks Wq/Wk/Wv ----
__global__ __launch_bounds__(256) void wtrans_kernel(const float* __restrict__ Wq,
                                                     const float* __restrict__ Wk,
                                                     const float* __restrict__ Wv,
                                                     short* __restrict__ Wt) {
    __shared__ float tile[32][33];
    const float* W = (blockIdx.z == 0) ? Wq : (blockIdx.z == 1) ? Wk : Wv;
    short* dst = Wt + (size_t)blockIdx.z * HD * FD;
    int h0 = blockIdx.x * 32, f0 = blockIdx.y * 32;
    int tx = threadIdx.x, ty = threadIdx.y;
    for (int j = ty; j < 32; j += 8)
        tile[j][tx] = W[(size_t)(f0 + j) * HD + h0 + tx];
    __syncthreads();
    for (int j = ty; j < 32; j += 8)
        dst[(size_t)(h0 + j) * FD + f0 + tx] = f2bf(tile[tx][j]);
}

// ---- Q/K projections ----
__global__ __launch_bounds__(256, 4) void projqk_kernel(const short* __restrict__ Xq,
                                                        const short* __restrict__ Xe,
                                                        const short* __restrict__ Wt3,
                                                        const float* __restrict__ bq,
                                                        const float* __restrict__ bk,
                                                        short* __restrict__ Q,
                                                        short* __restrict__ K) {
    __shared__ short As[128 * 64];
    __shared__ short Bs[128 * 64];
    int tid = threadIdx.x;
    int wave = tid >> 6, lane = tid & 63;
    int p = blockIdx.z;
    const short* X = (p == 0) ? Xq : Xe;
    const short* Wt = Wt3 + (size_t)p * HD * FD;
    const float* bias = (p == 0) ? bq : bk;
    short* O = (p == 0) ? Q : K;
    int bid = blockIdx.x;              // XCD swizzle: m-groups bound to XCDs
    int xcd = bid & 7;
    int idx = bid >> 3;
    int n_t = idx & 7;
    int m_t = (idx >> 3) * 8 + xcd;
    int tile_m = m_t * 128;
    int tile_n = n_t * 128;
    f32x16 acc[2][2] = ACC_INIT;
    gemm128_core<false>(X + (size_t)tile_m * FD, FD, Wt + (size_t)tile_n * FD, FD, FD,
                        As, Bs, acc, tid);
#pragma unroll
    for (int nt = 0; nt < 2; ++nt) {
        int gn = EPI_GN(nt);
        float bv_ = bias[gn];
#pragma unroll
        for (int mt = 0; mt < 2; ++mt)
#pragma unroll
            for (int r = 0; r < 16; ++r) {
                int gm = EPI_GM(mt, r);
                O[(size_t)gm * HD + gn] = f2bf(acc[mt][nt][r] + bv_);
            }
    }
}

// ---- V projection, transposed natively: Vt[b][h][t] = Wtv[h,:].Xe[b,t,:] + bv[h], fp16 out ----
__global__ __launch_bounds__(256, 4) void projv_kernel(const short* __restrict__ Xe,
                                                       const short* __restrict__ Wtv,
                                                       const float* __restrict__ bv,
                                                       short* __restrict__ Vt) {
    __shared__ short As[128 * 64];
    __shared__ short Bs[128 * 64];
    int tid = threadIdx.x;
    int wave = tid >> 6, lane = tid & 63;
    int id = blockIdx.x;
    int b = id & 7;                    // batch -> XCD binding
    int i = id >> 3;
    int n_t = i & 15;                  // over TKv
    int m_t = i >> 4;                  // over HD
    int tile_m = m_t * 128;
    int tile_n = n_t * 128;
    const short* Xb = Xe + (size_t)b * TKv * FD;
    f32x16 acc[2][2] = ACC_INIT;
    gemm128_core<false>(Wtv + (size_t)tile_m * FD, FD, Xb + (size_t)tile_n * FD, FD, FD,
                        As, Bs, acc, tid);
    short* Ob = Vt + (size_t)b * HD * TKv;
#pragma unroll
    for (int mt = 0; mt < 2; ++mt)
#pragma unroll
        for (int r = 0; r < 16; ++r) {
            int gm = EPI_GM(mt, r);     // h
            float bv_ = bv[gm];
#pragma unroll
            for (int nt = 0; nt < 2; ++nt) {
                int gn = EPI_GN(nt);    // t
                union { _Float16 h; short s; } cv;
                cv.h = (_Float16)(acc[mt][nt][r] + bv_);
                Ob[(size_t)gm * TKv + gn] = cv.s;
            }
        }
}

// ---- mask int32 -> bitmask u64 (ballot), + zero row-sum array L ----
__global__ __launch_bounds__(256) void maskbits_kernel(const int* __restrict__ mask,
                                                       unsigned long long* __restrict__ Mbits,
                                                       float* __restrict__ L) {
    int tid = threadIdx.x;
    int lane = tid & 63;
    if (blockIdx.x < 64) L[blockIdx.x * 256 + tid] = 0.f;
    const int NW = NB * TQv * (TKv / 64);
    int stride = gridDim.x * 4;
    for (int w = blockIdx.x * 4 + (tid >> 6); w < NW; w += stride) {
        int v = mask[(size_t)w * 64 + lane];
        unsigned long long bal = __ballot(v != 0);
        if (lane == 0) Mbits[w] = bal;
    }
}

// ---- score: P' = mask ? exp(QK/32 - 4) : 0 (fp16), row partials -> atomicAdd L ----
__global__ __launch_bounds__(256, 4) void score_kernel(const short* __restrict__ Q,
                                                       const short* __restrict__ K,
                                                       const unsigned long long* __restrict__ Mbits,
                                                       short* __restrict__ S,
                                                       float* __restrict__ L) {
    __shared__ short As[128 * 64];
    __shared__ short Bs[128 * 64];
    int tid = threadIdx.x;
    int wave = tid >> 6, lane = tid & 63;
    int id = blockIdx.x;
    int b = id & 7;                    // batch -> XCD binding
    int i = id >> 3;
    int n_t = i & 15;
    int m_t = i >> 4;
    int tile_m = m_t * 128;
    int tile_n = n_t * 128;
    const short* Aq = Q + (size_t)b * TQv * HD;
    const short* Bk = K + (size_t)b * TKv * HD;
    f32x16 acc[2][2] = ACC_INIT;
    gemm128_core<false>(Aq + (size_t)tile_m * HD, HD, Bk + (size_t)tile_n * HD, HD, HD,
                        As, Bs, acc, tid);
    short* Sb = S + (size_t)b * TQv * TKv;
    const unsigned long long* Mb = Mbits + (size_t)b * TQv * (TKv / 64);
    float* Lb = L + (size_t)b * TQv;
    int wofs = (tile_n >> 6) + (wave >> 1);
    int l31 = lane & 31;
#pragma unroll
    for (int mt = 0; mt < 2; ++mt)
#pragma unroll
        for (int r = 0; r < 16; ++r) {
            int gm = EPI_GM(mt, r);
            unsigned long long bits = Mb[(size_t)gm * (TKv / 64) + wofs];
            float rs = 0.f;
#pragma unroll
            for (int nt = 0; nt < 2; ++nt) {
                int gn = EPI_GN(nt);
                float s = acc[mt][nt][r] * 0.03125f;
                float p = ((bits >> (nt * 32 + l31)) & 1ULL)
                              ? exp2f((s - 4.0f) * 1.44269504f) : 0.f;
                rs += p;
                union { _Float16 h; short sh; } cv;
                cv.h = (_Float16)p;
                Sb[(size_t)gm * TKv + gn] = cv.sh;
            }
            for (int sh = 1; sh < 32; sh <<= 1) rs += __shfl_xor(rs, sh);
            if (l31 == 0) atomicAdd(&Lb[gm], rs);
        }
}

// ---- pv: O = (P' . Vt^T) / L, fp16 MFMA, fp32 out ----
__global__ __launch_bounds__(256, 4) void pv_kernel(const short* __restrict__ P,
                                                    const short* __restrict__ Vt,
                                                    const float* __restrict__ L,
                                                    float* __restrict__ Out) {
    __shared__ short As[128 * 64];
    __shared__ short Bs[128 * 64];
    int tid = threadIdx.x;
    int wave = tid >> 6, lane = tid & 63;
    int id = blockIdx.x;
    int b = id & 7;                    // batch -> XCD binding
    int i = id >> 3;
    int n_t = i & 7;                   // over HD
    int m_t = i >> 3;                  // over TQv
    int tile_m = m_t * 128;
    int tile_n = n_t * 128;
    const short* Ap = P + (size_t)b * TQv * TKv;
    const short* Bv = Vt + (size_t)b * HD * TKv;
    const float* Lb = L + (size_t)b * TQv;
    f32x16 acc[2][2] = ACC_INIT;
    gemm128_core<true>(Ap + (size_t)tile_m * TKv, TKv, Bv + (size_t)tile_n * TKv, TKv, TKv,
                       As, Bs, acc, tid);
    float* Ob = Out + (size_t)b * TQv * HD;
#pragma unroll
    for (int mt = 0; mt < 2; ++mt)
#pragma unroll
        for (int r = 0; r < 16; ++r) {
            int gm = EPI_GM(mt, r);
            float l = Lb[gm];
            float inv = (l > 0.f) ? 1.f / l : 0.f;
#pragma unroll
            for (int nt = 0; nt < 2; ++nt) {
                int gn = EPI_GN(nt);
                Ob[(size_t)gm * HD + gn] = acc[mt][nt][r] * inv;
            }
        }
}

extern "C" void kernel_launch(void* const* d_in, const int* in_sizes, int n_in,
                              void* d_out, int out_size, void* d_ws, size_t ws_size,
                              hipStream_t stream) {
    const float* query = (const float*)d_in[0];
    const float* enc   = (const float*)d_in[1];
    const int*   mask  = (const int*)d_in[2];
    const float* Wq    = (const float*)d_in[3];
    const float* bq    = (const float*)d_in[4];
    const float* Wk    = (const float*)d_in[5];
    const float* bk    = (const float*)d_in[6];
    const float* Wv    = (const float*)d_in[7];
    const float* bv    = (const float*)d_in[8];
    float* out = (float*)d_out;

    // workspace layout (bytes); total 174,063,616
    //   [0, 6.29MB): Wtq/Wtk/Wtv bf16 (wtrans -> projqk/projv), then reused as
    //     Mbits [0,4MB) + L [4MB,4MB+64KB) once the Wt copies are dead.
    //   S (fp16 P', 67MB) aliases Xq+Xe (dead after projqk/projv).
    char* ws = (char*)d_ws;
    short* Wt  = (short*)(ws);
    unsigned long long* Mbits = (unsigned long long*)(ws);
    float* L   = (float*)(ws + 4194304);
    short* Xq  = (short*)(ws + 6291456);
    short* Xe  = (short*)(ws + 39845888);
    short* S   = (short*)(ws + 6291456);       // aliases Xq,Xe
    short* Qb  = (short*)(ws + 73400320);
    short* Kb  = (short*)(ws + 106954752);
    short* Vt  = (short*)(ws + 140509184);
    (void)in_sizes; (void)n_in; (void)out_size; (void)ws_size;

    convert_kernel<<<dim3(8192, 2), 256, 0, stream>>>(query, enc, Xq, Xe);
    wtrans_kernel<<<dim3(32, 32, 3), dim3(32, 8), 0, stream>>>(Wq, Wk, Wv, Wt);
    projqk_kernel<<<dim3(1024, 1, 2), 256, 0, stream>>>(Xq, Xe, Wt, bq, bk, Qb, Kb);
    projv_kernel<<<dim3(1024), 256, 0, stream>>>(Xe, Wt + (size_t)2 * HD * FD, bv, Vt);
    maskbits_kernel<<<dim3(2048), 256, 0, stream>>>(mask, Mbits, L);
    score_kernel<<<dim3(2048), 256, 0, stream>>>(Qb, Kb, Mbits, S, L);
    pv_kernel<<<dim3(1024), 256, 0, stream>>>(S, Vt, L, out);
}